// Round 2
// baseline (1666.170 us; speedup 1.0000x reference)
//
#include <hip/hip_runtime.h>
#include <cstdint>
#include <cstddef>

typedef _Float16 f16x8 __attribute__((ext_vector_type(8)));
typedef _Float16 f16x4 __attribute__((ext_vector_type(4)));
typedef _Float16 f16x2 __attribute__((ext_vector_type(2)));
typedef float    f32x4 __attribute__((ext_vector_type(4)));

__device__ __forceinline__ void async16(const void* g, void* l) {
  __builtin_amdgcn_global_load_lds(
      (const __attribute__((address_space(1))) void*)g,
      (__attribute__((address_space(3))) void*)l, 16, 0, 0);
}

// ---------------- fp32 -> fp16 convert ----------------
__global__ void cvt_kernel(const float* __restrict__ in, _Float16* __restrict__ out, int n4) {
  int i = blockIdx.x * blockDim.x + threadIdx.x;
  int stride = gridDim.x * blockDim.x;
  for (; i < n4; i += stride) {
    float4 f = ((const float4*)in)[i];
    f16x4 o;
    o[0] = (_Float16)f.x; o[1] = (_Float16)f.y;
    o[2] = (_Float16)f.z; o[3] = (_Float16)f.w;
    ((f16x4*)out)[i] = o;
  }
}

// ---------------- RoPE, interleaved pairs, in place ----------------
__global__ void rope_kernel(_Float16* __restrict__ X, const int* __restrict__ sp,
                            int ppShift, int sMask, int nPairs) {
  int i = blockIdx.x * blockDim.x + threadIdx.x;
  int stride = gridDim.x * blockDim.x;
  int start = *sp;
  for (int p = i; p < nPairs; p += stride) {
    int row = p >> ppShift;
    int pc  = p & ((1 << ppShift) - 1);
    int fi  = pc & 63;                 // pair index within head (d/2 = 64)
    int s   = row & sMask;             // row = b*S + s
    float ang = (float)(start + s) * exp2f(-0.20762050593046014f * (float)fi);
    float sn, cs;
    __sincosf(ang, &sn, &cs);
    uint32_t u = ((uint32_t*)X)[p];
    f16x2 v = __builtin_bit_cast(f16x2, u);
    float x1 = (float)v[0], x2 = (float)v[1];
    v[0] = (_Float16)(x1 * cs - x2 * sn);
    v[1] = (_Float16)(x1 * sn + x2 * cs);
    ((uint32_t*)X)[p] = __builtin_bit_cast(uint32_t, v);
  }
}

// ---------------- NT GEMM: C = A(M,K) * B(N,K)^T ----------------
// OUT_MODE 0: f16 C row-major (ld=N)
// OUT_MODE 2: f32 C row-major (ld=N)
// OUT_MODE 3: split KV: cols [0,N/2) -> f16 Cp (ld=N/2); cols [N/2,N) -> f16 Cp2 transposed (ld=M)
template<int OUT_MODE>
__global__ __launch_bounds__(256, 3)
void gemm_nt(const _Float16* __restrict__ A, const _Float16* __restrict__ B,
             void* __restrict__ Cp, void* __restrict__ Cp2,
             int M, int N, int K) {
  __shared__ __align__(16) _Float16 As[128 * 64];
  __shared__ __align__(16) _Float16 Bs[128 * 64];
  const int tid  = threadIdx.x;
  const int wave = tid >> 6, lane = tid & 63;
  const int l15  = lane & 15, quad = lane >> 4;
  const int m0 = blockIdx.y * 128, n0 = blockIdx.x * 128;
  const int wm = (wave >> 1) * 64, wn = (wave & 1) * 64;
  f32x4 acc[4][4] = {};
  const int cbase = wave * 256;

  for (int kb = 0; kb < K; kb += 64) {
    // stage A,B tiles (128x64 f16 each) via global_load_lds, XOR chunk swizzle
    #pragma unroll
    for (int i = 0; i < 4; ++i) {
      int base = cbase + i * 64;
      int idx  = base + lane;          // chunk 0..1023
      int row  = idx >> 3, pos = idx & 7;
      int c    = pos ^ (row & 7);
      async16(A + (size_t)(m0 + row) * K + kb + c * 8, (char*)As + base * 16);
      async16(B + (size_t)(n0 + row) * K + kb + c * 8, (char*)Bs + base * 16);
    }
    __syncthreads();
    #pragma unroll
    for (int ks = 0; ks < 2; ++ks) {
      f16x8 af[4], bfv[4];
      #pragma unroll
      for (int t = 0; t < 4; ++t) {
        int ra = wm + t * 16 + l15;
        int pa = (ks * 4 + quad) ^ (ra & 7);
        af[t] = *(const f16x8*)((const char*)As + ra * 128 + pa * 16);
        int rb = wn + t * 16 + l15;
        int pb = (ks * 4 + quad) ^ (rb & 7);
        bfv[t] = *(const f16x8*)((const char*)Bs + rb * 128 + pb * 16);
      }
      #pragma unroll
      for (int mt = 0; mt < 4; ++mt)
        #pragma unroll
        for (int nt = 0; nt < 4; ++nt)
          acc[mt][nt] = __builtin_amdgcn_mfma_f32_16x16x32_f16(af[mt], bfv[nt], acc[mt][nt], 0, 0, 0);
    }
    __syncthreads();
  }

  if constexpr (OUT_MODE == 0) {
    _Float16* Cb = (_Float16*)Cp;
    #pragma unroll
    for (int mt = 0; mt < 4; ++mt)
      #pragma unroll
      for (int r = 0; r < 4; ++r) {
        size_t row = (size_t)(m0 + wm + mt * 16 + quad * 4 + r);
        #pragma unroll
        for (int nt = 0; nt < 4; ++nt)
          Cb[row * N + n0 + wn + nt * 16 + l15] = (_Float16)acc[mt][nt][r];
      }
  } else if constexpr (OUT_MODE == 2) {
    float* Cf = (float*)Cp;
    #pragma unroll
    for (int mt = 0; mt < 4; ++mt)
      #pragma unroll
      for (int r = 0; r < 4; ++r) {
        size_t row = (size_t)(m0 + wm + mt * 16 + quad * 4 + r);
        #pragma unroll
        for (int nt = 0; nt < 4; ++nt)
          Cf[row * N + n0 + wn + nt * 16 + l15] = acc[mt][nt][r];
      }
  } else if constexpr (OUT_MODE == 3) {
    const int half = N >> 1;
    if (n0 < half) {           // K-projection half: normal f16 store, ld = half
      _Float16* Cb = (_Float16*)Cp;
      #pragma unroll
      for (int mt = 0; mt < 4; ++mt)
        #pragma unroll
        for (int r = 0; r < 4; ++r) {
          size_t row = (size_t)(m0 + wm + mt * 16 + quad * 4 + r);
          #pragma unroll
          for (int nt = 0; nt < 4; ++nt)
            Cb[row * half + n0 + wn + nt * 16 + l15] = (_Float16)acc[mt][nt][r];
        }
    } else {                   // V-projection half: store transposed (feature-major)
      _Float16* Ct = (_Float16*)Cp2;
      #pragma unroll
      for (int mt = 0; mt < 4; ++mt)
        #pragma unroll
        for (int nt = 0; nt < 4; ++nt) {
          size_t crow = (size_t)(n0 - half + wn + nt * 16 + l15);
          size_t ccol = (size_t)(m0 + wm + mt * 16 + quad * 4);
          f16x4 t;
          t[0] = (_Float16)acc[mt][nt][0]; t[1] = (_Float16)acc[mt][nt][1];
          t[2] = (_Float16)acc[mt][nt][2]; t[3] = (_Float16)acc[mt][nt][3];
          *(f16x4*)(Ct + crow * M + ccol) = t;
        }
    }
  }
}

// ---------------- flash attention, non-causal, GQA 4:1 ----------------
// Q: (T, 4096) roped; Kg: (T, 1024) roped; Vt: (1024, T) transposed; O: (T, 4096)
// Single-buffered K/V (48KB LDS -> 3 blocks/CU), 2 barriers/iter with staged
// prefetch coverage; row-sums via MFMA-with-ones; mt-split SM->PV interleave.
__global__ __launch_bounds__(256, 3)
void flash_kernel(const _Float16* __restrict__ Q, const _Float16* __restrict__ Kg,
                  const _Float16* __restrict__ Vt, _Float16* __restrict__ O,
                  int S, int T) {
  __shared__ __align__(16) _Float16 Kt[64 * 128];   // [key][d], swizzled
  __shared__ __align__(16) _Float16 Vs[128 * 64];   // [d][key], swizzled
  __shared__ __align__(16) _Float16 Ps[4 * 32 * 64];// per-wave P [q][key], swizzled
  const int tid  = threadIdx.x;
  const int wave = tid >> 6, lane = tid & 63;
  const int l15  = lane & 15, quad = lane >> 4;
  const int qt = blockIdx.x, hq = blockIdx.y, b = blockIdx.z;
  const int kvh = hq >> 2;
  const float scale = 0.12751744f;   // log2(e)/sqrt(128): softmax in exp2 domain

  // Q fragments in registers: wave owns 32 q-rows
  f16x8 qf[2][4];
  #pragma unroll
  for (int mt = 0; mt < 2; ++mt)
    #pragma unroll
    for (int ks = 0; ks < 4; ++ks) {
      size_t row = (size_t)b * S + qt * 128 + wave * 32 + mt * 16 + l15;
      qf[mt][ks] = *(const f16x8*)(Q + row * 4096 + hq * 128 + ks * 32 + quad * 8);
    }

  const f16x8 ones = {(_Float16)1, (_Float16)1, (_Float16)1, (_Float16)1,
                      (_Float16)1, (_Float16)1, (_Float16)1, (_Float16)1};

  f32x4 oacc[2][8] = {};
  f32x4 liacc[2] = {};              // row-sums accumulated by MFMA(P, ones)
  float mi[2][4];
  #pragma unroll
  for (int mt = 0; mt < 2; ++mt)
    #pragma unroll
    for (int r = 0; r < 4; ++r) mi[mt][r] = -1e30f;

  const int nkt = S >> 6;

  auto stageK = [&](int kt) {
    #pragma unroll
    for (int i = 0; i < 4; ++i) {
      int base = wave * 256 + i * 64;
      int idx  = base + lane;
      int row = idx >> 4, pos = idx & 15, c = pos ^ (row & 15);
      async16(Kg + (size_t)(b * S + kt * 64 + row) * 1024 + kvh * 128 + c * 8,
              (char*)Kt + base * 16);
    }
  };
  auto stageV = [&](int kt) {
    #pragma unroll
    for (int i = 0; i < 4; ++i) {
      int base = wave * 256 + i * 64;
      int idx  = base + lane;
      int row = idx >> 3, pos = idx & 7, c = pos ^ (row & 7);
      async16(Vt + (size_t)(kvh * 128 + row) * T + b * S + kt * 64 + c * 8,
              (char*)Vs + base * 16);
    }
  };

  stageK(0); stageV(0);
  __syncthreads();           // drain prologue

  for (int kt = 0; kt < nkt; ++kt) {
    // ---- S = Q K^T  (reads Kt = K[kt], drained at prior barrier) ----
    f32x4 sacc[2][4] = {};
    #pragma unroll
    for (int ks = 0; ks < 4; ++ks) {
      f16x8 kf[4];
      #pragma unroll
      for (int nt = 0; nt < 4; ++nt) {
        int rk = nt * 16 + l15;
        int pp = (ks * 4 + quad) ^ (rk & 15);
        kf[nt] = *(const f16x8*)((const char*)Kt + rk * 256 + pp * 16);
      }
      __builtin_amdgcn_s_setprio(1);
      #pragma unroll
      for (int mt = 0; mt < 2; ++mt)
        #pragma unroll
        for (int nt = 0; nt < 4; ++nt)
          sacc[mt][nt] = __builtin_amdgcn_mfma_f32_16x16x32_f16(qf[mt][ks], kf[nt], sacc[mt][nt], 0, 0, 0);
      __builtin_amdgcn_s_setprio(0);
    }

    // barrier A: all waves done reading K[kt]; drains V[kt] stage (issued last iter)
    __syncthreads();
    if (kt + 1 < nkt) stageK(kt + 1);   // covered by SM+PV, drained at barrier B

    // ---- per-16-row half: softmax then PV (PV MFMAs overlap next half's VALU) ----
    #pragma unroll
    for (int mt = 0; mt < 2; ++mt) {
      // raw-domain row max: in-reg over nt, then 16-lane butterfly
      float mx[4];
      #pragma unroll
      for (int r = 0; r < 4; ++r)
        mx[r] = fmaxf(fmaxf(sacc[mt][0][r], sacc[mt][1][r]),
                      fmaxf(sacc[mt][2][r], sacc[mt][3][r]));
      #pragma unroll
      for (int d = 1; d < 16; d <<= 1)
        #pragma unroll
        for (int r = 0; r < 4; ++r)
          mx[r] = fmaxf(mx[r], __shfl_xor(mx[r], d));
      // defer-max: rescale only when running max grew materially (24 raw ~ 2^3)
      bool grow = false;
      #pragma unroll
      for (int r = 0; r < 4; ++r) grow = grow || (mx[r] > mi[mt][r] + 24.0f);
      if (__any(grow)) {
        #pragma unroll
        for (int r = 0; r < 4; ++r) {
          float mnew = fmaxf(mi[mt][r], mx[r]);
          float al = exp2f((mi[mt][r] - mnew) * scale);
          mi[mt][r] = mnew;
          liacc[mt][r] *= al;
          #pragma unroll
          for (int nt = 0; nt < 8; ++nt) oacc[mt][nt][r] *= al;
        }
      }
      float nm[4];
      #pragma unroll
      for (int r = 0; r < 4; ++r) nm[r] = -mi[mt][r] * scale;
      #pragma unroll
      for (int nt = 0; nt < 4; ++nt)
        #pragma unroll
        for (int r = 0; r < 4; ++r)
          sacc[mt][nt][r] = exp2f(fmaf(sacc[mt][nt][r], scale, nm[r]));
      // P -> LDS (C-layout to A-operand layout round trip), swizzled
      #pragma unroll
      for (int nt = 0; nt < 4; ++nt)
        #pragma unroll
        for (int r = 0; r < 4; ++r) {
          int prow = mt * 16 + quad * 4 + r;
          int key  = nt * 16 + l15;
          int pos  = (key >> 3) ^ (prow & 7);
          Ps[wave * 2048 + prow * 64 + pos * 8 + (key & 7)] = (_Float16)sacc[mt][nt][r];
        }
      // ---- O[mt] += P[mt] V ; li[mt] += P[mt]·1 (row-sum via MFMA) ----
      #pragma unroll
      for (int k2 = 0; k2 < 2; ++k2) {
        int rp = mt * 16 + l15;
        int ppp = (k2 * 4 + quad) ^ (rp & 7);
        f16x8 pf = *(const f16x8*)((const char*)Ps + wave * 4096 + rp * 128 + ppp * 16);
        f16x8 vf[8];
        #pragma unroll
        for (int nt = 0; nt < 8; ++nt) {
          int rv = nt * 16 + l15;
          int pv = (k2 * 4 + quad) ^ (rv & 7);
          vf[nt] = *(const f16x8*)((const char*)Vs + rv * 128 + pv * 16);
        }
        __builtin_amdgcn_s_setprio(1);
        liacc[mt] = __builtin_amdgcn_mfma_f32_16x16x32_f16(pf, ones, liacc[mt], 0, 0, 0);
        #pragma unroll
        for (int nt = 0; nt < 8; ++nt)
          oacc[mt][nt] = __builtin_amdgcn_mfma_f32_16x16x32_f16(pf, vf[nt], oacc[mt][nt], 0, 0, 0);
        __builtin_amdgcn_s_setprio(0);
      }
    }

    // barrier B: all waves done reading V[kt]; drains K[kt+1] stage
    __syncthreads();
    if (kt + 1 < nkt) stageV(kt + 1);   // covered by next QK, drained at barrier A
  }

  // epilogue: O / l  (liacc identical across cols; lane reads its own)
  #pragma unroll
  for (int mt = 0; mt < 2; ++mt)
    #pragma unroll
    for (int r = 0; r < 4; ++r) {
      float inv = 1.0f / liacc[mt][r];
      size_t row = (size_t)b * S + qt * 128 + wave * 32 + mt * 16 + quad * 4 + r;
      #pragma unroll
      for (int nt = 0; nt < 8; ++nt)
        O[row * 4096 + hq * 128 + nt * 16 + l15] = (_Float16)(oacc[mt][nt][r] * inv);
    }
}

extern "C" void kernel_launch(void* const* d_in, const int* in_sizes, int n_in,
                              void* d_out, int out_size, void* d_ws, size_t ws_size,
                              hipStream_t stream) {
  const float* x  = (const float*)d_in[0];
  const float* wq = (const float*)d_in[1];
  const float* wk = (const float*)d_in[2];
  const float* wv = (const float*)d_in[3];
  const float* wo = (const float*)d_in[4];
  const int*   sp = (const int*)d_in[5];

  const int dim = 4096, kvdim = 1024;
  const int T = in_sizes[0] / dim;   // 4096 tokens (b*s)
  const int B = 2;
  const int S = T / B;               // 2048

  // workspace layout (fp16), total ~160 MiB
  _Float16* xb   = (_Float16*)d_ws;
  _Float16* wqb  = xb   + (size_t)T * dim;
  _Float16* wkvb = wqb  + (size_t)dim * dim;
  _Float16* wob  = wkvb + (size_t)2 * kvdim * dim;
  _Float16* XQ   = wob  + (size_t)dim * dim;
  _Float16* XK   = XQ   + (size_t)T * dim;
  _Float16* VT   = XK   + (size_t)T * kvdim;
  _Float16* AO   = xb;               // alias: xb dead after projections

  auto cvt = [&](const float* src, _Float16* dst, size_t n) {
    int n4 = (int)(n / 4);
    int blocks = (n4 + 255) / 256;
    if (blocks > 4096) blocks = 4096;
    cvt_kernel<<<blocks, 256, 0, stream>>>(src, dst, n4);
  };
  cvt(x,  xb,  (size_t)T * dim);
  cvt(wq, wqb, (size_t)dim * dim);
  cvt(wk, wkvb, (size_t)kvdim * dim);
  cvt(wv, wkvb + (size_t)kvdim * dim, (size_t)kvdim * dim);
  cvt(wo, wob, (size_t)dim * dim);

  // projections
  gemm_nt<0><<<dim3(dim / 128, T / 128), 256, 0, stream>>>(xb, wqb, XQ, nullptr, T, dim, dim);
  gemm_nt<3><<<dim3((2 * kvdim) / 128, T / 128), 256, 0, stream>>>(xb, wkvb, XK, VT, T, 2 * kvdim, dim);

  // RoPE (in place)
  rope_kernel<<<4096, 256, 0, stream>>>(XQ, sp, 11, S - 1, T * dim / 2);
  rope_kernel<<<2048, 256, 0, stream>>>(XK, sp,  9, S - 1, T * kvdim / 2);

  // attention
  flash_kernel<<<dim3(S / 128, 32, B), 256, 0, stream>>>(XQ, XK, VT, AO, S, T);

  // output projection (fp32 out)
  gemm_nt<2><<<dim3(dim / 128, T / 128), 256, 0, stream>>>(AO, wob, d_out, nullptr, T, dim, dim);
}

// Round 3
// 863.764 us; speedup vs baseline: 1.9290x; 1.9290x over previous
//
#include <hip/hip_runtime.h>
#include <cstdint>
#include <cstddef>

typedef _Float16 f16x8 __attribute__((ext_vector_type(8)));
typedef _Float16 f16x4 __attribute__((ext_vector_type(4)));
typedef _Float16 f16x2 __attribute__((ext_vector_type(2)));
typedef float    f32x4 __attribute__((ext_vector_type(4)));

__device__ __forceinline__ void async16(const void* g, void* l) {
  __builtin_amdgcn_global_load_lds(
      (const __attribute__((address_space(1))) void*)g,
      (__attribute__((address_space(3))) void*)l, 16, 0, 0);
}

// ---------------- fp32 -> fp16 convert ----------------
__global__ void cvt_kernel(const float* __restrict__ in, _Float16* __restrict__ out, int n4) {
  int i = blockIdx.x * blockDim.x + threadIdx.x;
  int stride = gridDim.x * blockDim.x;
  for (; i < n4; i += stride) {
    float4 f = ((const float4*)in)[i];
    f16x4 o;
    o[0] = (_Float16)f.x; o[1] = (_Float16)f.y;
    o[2] = (_Float16)f.z; o[3] = (_Float16)f.w;
    ((f16x4*)out)[i] = o;
  }
}

// ---------------- RoPE, interleaved pairs, in place ----------------
__global__ void rope_kernel(_Float16* __restrict__ X, const int* __restrict__ sp,
                            int ppShift, int sMask, int nPairs) {
  int i = blockIdx.x * blockDim.x + threadIdx.x;
  int stride = gridDim.x * blockDim.x;
  int start = *sp;
  for (int p = i; p < nPairs; p += stride) {
    int row = p >> ppShift;
    int pc  = p & ((1 << ppShift) - 1);
    int fi  = pc & 63;                 // pair index within head (d/2 = 64)
    int s   = row & sMask;             // row = b*S + s
    float ang = (float)(start + s) * exp2f(-0.20762050593046014f * (float)fi);
    float sn, cs;
    __sincosf(ang, &sn, &cs);
    uint32_t u = ((uint32_t*)X)[p];
    f16x2 v = __builtin_bit_cast(f16x2, u);
    float x1 = (float)v[0], x2 = (float)v[1];
    v[0] = (_Float16)(x1 * cs - x2 * sn);
    v[1] = (_Float16)(x1 * sn + x2 * cs);
    ((uint32_t*)X)[p] = __builtin_bit_cast(uint32_t, v);
  }
}

// ---------------- NT GEMM: C = A(M,K) * B(N,K)^T ----------------
// OUT_MODE 0: f16 C row-major (ld=N)
// OUT_MODE 2: f32 C row-major (ld=N)
// OUT_MODE 3: split KV: cols [0,N/2) -> f16 Cp (ld=N/2); cols [N/2,N) -> f16 Cp2 transposed (ld=M)
template<int OUT_MODE>
__global__ __launch_bounds__(256, 3)
void gemm_nt(const _Float16* __restrict__ A, const _Float16* __restrict__ B,
             void* __restrict__ Cp, void* __restrict__ Cp2,
             int M, int N, int K) {
  __shared__ __align__(16) _Float16 As[128 * 64];
  __shared__ __align__(16) _Float16 Bs[128 * 64];
  const int tid  = threadIdx.x;
  const int wave = tid >> 6, lane = tid & 63;
  const int l15  = lane & 15, quad = lane >> 4;
  const int m0 = blockIdx.y * 128, n0 = blockIdx.x * 128;
  const int wm = (wave >> 1) * 64, wn = (wave & 1) * 64;
  f32x4 acc[4][4] = {};
  const int cbase = wave * 256;

  for (int kb = 0; kb < K; kb += 64) {
    // stage A,B tiles (128x64 f16 each) via global_load_lds, XOR chunk swizzle
    #pragma unroll
    for (int i = 0; i < 4; ++i) {
      int base = cbase + i * 64;
      int idx  = base + lane;          // chunk 0..1023
      int row  = idx >> 3, pos = idx & 7;
      int c    = pos ^ (row & 7);
      async16(A + (size_t)(m0 + row) * K + kb + c * 8, (char*)As + base * 16);
      async16(B + (size_t)(n0 + row) * K + kb + c * 8, (char*)Bs + base * 16);
    }
    __syncthreads();
    #pragma unroll
    for (int ks = 0; ks < 2; ++ks) {
      f16x8 af[4], bfv[4];
      #pragma unroll
      for (int t = 0; t < 4; ++t) {
        int ra = wm + t * 16 + l15;
        int pa = (ks * 4 + quad) ^ (ra & 7);
        af[t] = *(const f16x8*)((const char*)As + ra * 128 + pa * 16);
        int rb = wn + t * 16 + l15;
        int pb = (ks * 4 + quad) ^ (rb & 7);
        bfv[t] = *(const f16x8*)((const char*)Bs + rb * 128 + pb * 16);
      }
      #pragma unroll
      for (int mt = 0; mt < 4; ++mt)
        #pragma unroll
        for (int nt = 0; nt < 4; ++nt)
          acc[mt][nt] = __builtin_amdgcn_mfma_f32_16x16x32_f16(af[mt], bfv[nt], acc[mt][nt], 0, 0, 0);
    }
    __syncthreads();
  }

  if constexpr (OUT_MODE == 0) {
    _Float16* Cb = (_Float16*)Cp;
    #pragma unroll
    for (int mt = 0; mt < 4; ++mt)
      #pragma unroll
      for (int r = 0; r < 4; ++r) {
        size_t row = (size_t)(m0 + wm + mt * 16 + quad * 4 + r);
        #pragma unroll
        for (int nt = 0; nt < 4; ++nt)
          Cb[row * N + n0 + wn + nt * 16 + l15] = (_Float16)acc[mt][nt][r];
      }
  } else if constexpr (OUT_MODE == 2) {
    float* Cf = (float*)Cp;
    #pragma unroll
    for (int mt = 0; mt < 4; ++mt)
      #pragma unroll
      for (int r = 0; r < 4; ++r) {
        size_t row = (size_t)(m0 + wm + mt * 16 + quad * 4 + r);
        #pragma unroll
        for (int nt = 0; nt < 4; ++nt)
          Cf[row * N + n0 + wn + nt * 16 + l15] = acc[mt][nt][r];
      }
  } else if constexpr (OUT_MODE == 3) {
    const int half = N >> 1;
    if (n0 < half) {           // K-projection half: normal f16 store, ld = half
      _Float16* Cb = (_Float16*)Cp;
      #pragma unroll
      for (int mt = 0; mt < 4; ++mt)
        #pragma unroll
        for (int r = 0; r < 4; ++r) {
          size_t row = (size_t)(m0 + wm + mt * 16 + quad * 4 + r);
          #pragma unroll
          for (int nt = 0; nt < 4; ++nt)
            Cb[row * half + n0 + wn + nt * 16 + l15] = (_Float16)acc[mt][nt][r];
        }
    } else {                   // V-projection half: store transposed (feature-major)
      _Float16* Ct = (_Float16*)Cp2;
      #pragma unroll
      for (int mt = 0; mt < 4; ++mt)
        #pragma unroll
        for (int nt = 0; nt < 4; ++nt) {
          size_t crow = (size_t)(n0 - half + wn + nt * 16 + l15);
          size_t ccol = (size_t)(m0 + wm + mt * 16 + quad * 4);
          f16x4 t;
          t[0] = (_Float16)acc[mt][nt][0]; t[1] = (_Float16)acc[mt][nt][1];
          t[2] = (_Float16)acc[mt][nt][2]; t[3] = (_Float16)acc[mt][nt][3];
          *(f16x4*)(Ct + crow * M + ccol) = t;
        }
    }
  }
}

// ---------------- flash attention, non-causal, GQA 4:1 ----------------
// Q: (T, 4096) roped; Kg: (T, 1024) roped; Vt: (1024, T) transposed; O: (T, 4096)
// Single-buffered K/V (48KB LDS -> 3 blocks/CU via LDS, NOT launch_bounds:
// R2 showed __launch_bounds__(256,3) forces the allocator into scratch spills,
// FETCH 82MB->1.15GB).  launch_bounds stays (256,2); VGPR budget kept <=168 by
// loading V fragments in groups of 4 shared across both mt halves.
// Two barriers/iter: stageK hidden under softmax+PV, stageV hidden under QK.
// Row-sums via MFMA(P, ones): no sum shuffle-reduce, no li scalar bookkeeping.
__global__ __launch_bounds__(256, 2)
void flash_kernel(const _Float16* __restrict__ Q, const _Float16* __restrict__ Kg,
                  const _Float16* __restrict__ Vt, _Float16* __restrict__ O,
                  int S, int T) {
  __shared__ __align__(16) _Float16 Kt[64 * 128];   // [key][d], swizzled
  __shared__ __align__(16) _Float16 Vs[128 * 64];   // [d][key], swizzled
  __shared__ __align__(16) _Float16 Ps[4 * 32 * 64];// per-wave P [q][key], swizzled
  const int tid  = threadIdx.x;
  const int wave = tid >> 6, lane = tid & 63;
  const int l15  = lane & 15, quad = lane >> 4;
  const int qt = blockIdx.x, hq = blockIdx.y, b = blockIdx.z;
  const int kvh = hq >> 2;
  const float scale = 0.12751744f;   // log2(e)/sqrt(128): softmax in exp2 domain

  // Q fragments in registers: wave owns 32 q-rows
  f16x8 qf[2][4];
  #pragma unroll
  for (int mt = 0; mt < 2; ++mt)
    #pragma unroll
    for (int ks = 0; ks < 4; ++ks) {
      size_t row = (size_t)b * S + qt * 128 + wave * 32 + mt * 16 + l15;
      qf[mt][ks] = *(const f16x8*)(Q + row * 4096 + hq * 128 + ks * 32 + quad * 8);
    }

  const f16x8 ones = {(_Float16)1, (_Float16)1, (_Float16)1, (_Float16)1,
                      (_Float16)1, (_Float16)1, (_Float16)1, (_Float16)1};

  f32x4 oacc[2][8] = {};
  f32x4 liacc[2] = {};              // row-sums accumulated by MFMA(P, ones)
  float mi[2][4];
  #pragma unroll
  for (int mt = 0; mt < 2; ++mt)
    #pragma unroll
    for (int r = 0; r < 4; ++r) mi[mt][r] = -1e30f;

  const int nkt = S >> 6;

  auto stageK = [&](int kt) {
    #pragma unroll
    for (int i = 0; i < 4; ++i) {
      int base = wave * 256 + i * 64;
      int idx  = base + lane;
      int row = idx >> 4, pos = idx & 15, c = pos ^ (row & 15);
      async16(Kg + (size_t)(b * S + kt * 64 + row) * 1024 + kvh * 128 + c * 8,
              (char*)Kt + base * 16);
    }
  };
  auto stageV = [&](int kt) {
    #pragma unroll
    for (int i = 0; i < 4; ++i) {
      int base = wave * 256 + i * 64;
      int idx  = base + lane;
      int row = idx >> 3, pos = idx & 7, c = pos ^ (row & 7);
      async16(Vt + (size_t)(kvh * 128 + row) * T + b * S + kt * 64 + c * 8,
              (char*)Vs + base * 16);
    }
  };

  stageK(0); stageV(0);
  __syncthreads();           // drain prologue

  for (int kt = 0; kt < nkt; ++kt) {
    // ---- S = Q K^T  (reads Kt = K[kt], drained at prior barrier) ----
    f32x4 sacc[2][4] = {};
    #pragma unroll
    for (int ks = 0; ks < 4; ++ks) {
      f16x8 kf[4];
      #pragma unroll
      for (int nt = 0; nt < 4; ++nt) {
        int rk = nt * 16 + l15;
        int pp = (ks * 4 + quad) ^ (rk & 15);
        kf[nt] = *(const f16x8*)((const char*)Kt + rk * 256 + pp * 16);
      }
      __builtin_amdgcn_s_setprio(1);
      #pragma unroll
      for (int mt = 0; mt < 2; ++mt)
        #pragma unroll
        for (int nt = 0; nt < 4; ++nt)
          sacc[mt][nt] = __builtin_amdgcn_mfma_f32_16x16x32_f16(qf[mt][ks], kf[nt], sacc[mt][nt], 0, 0, 0);
      __builtin_amdgcn_s_setprio(0);
    }

    // barrier A: all waves done reading K[kt]; drains V[kt] stage (issued last iter)
    __syncthreads();
    if (kt + 1 < nkt) stageK(kt + 1);   // covered by softmax+PV, drained at barrier B

    // ---- online softmax, both halves (raw-domain max, deferred rescale, exp2) ----
    #pragma unroll
    for (int mt = 0; mt < 2; ++mt) {
      float mx[4];
      #pragma unroll
      for (int r = 0; r < 4; ++r)
        mx[r] = fmaxf(fmaxf(sacc[mt][0][r], sacc[mt][1][r]),
                      fmaxf(sacc[mt][2][r], sacc[mt][3][r]));
      #pragma unroll
      for (int d = 1; d < 16; d <<= 1)
        #pragma unroll
        for (int r = 0; r < 4; ++r)
          mx[r] = fmaxf(mx[r], __shfl_xor(mx[r], d));
      // defer-max: rescale only when running max grew materially (24 raw ~ 2^3)
      bool grow = false;
      #pragma unroll
      for (int r = 0; r < 4; ++r) grow = grow || (mx[r] > mi[mt][r] + 24.0f);
      if (__any(grow)) {
        #pragma unroll
        for (int r = 0; r < 4; ++r) {
          float mnew = fmaxf(mi[mt][r], mx[r]);
          float al = exp2f((mi[mt][r] - mnew) * scale);
          mi[mt][r] = mnew;
          liacc[mt][r] *= al;
          #pragma unroll
          for (int nt = 0; nt < 8; ++nt) oacc[mt][nt][r] *= al;
        }
      }
      float nm[4];
      #pragma unroll
      for (int r = 0; r < 4; ++r) nm[r] = -mi[mt][r] * scale;
      #pragma unroll
      for (int nt = 0; nt < 4; ++nt)
        #pragma unroll
        for (int r = 0; r < 4; ++r)
          sacc[mt][nt][r] = exp2f(fmaf(sacc[mt][nt][r], scale, nm[r]));
      // P -> LDS (C-layout to A-operand layout round trip), swizzled
      #pragma unroll
      for (int nt = 0; nt < 4; ++nt)
        #pragma unroll
        for (int r = 0; r < 4; ++r) {
          int prow = mt * 16 + quad * 4 + r;
          int key  = nt * 16 + l15;
          int pos  = (key >> 3) ^ (prow & 7);
          Ps[wave * 2048 + prow * 64 + pos * 8 + (key & 7)] = (_Float16)sacc[mt][nt][r];
        }
    }

    // ---- O += P V ; li += P·1  (V fragments in groups of 4, shared across mt) ----
    #pragma unroll
    for (int k2 = 0; k2 < 2; ++k2) {
      f16x8 pf[2];
      #pragma unroll
      for (int mt = 0; mt < 2; ++mt) {
        int rp = mt * 16 + l15;
        int ppp = (k2 * 4 + quad) ^ (rp & 7);
        pf[mt] = *(const f16x8*)((const char*)Ps + wave * 4096 + rp * 128 + ppp * 16);
      }
      #pragma unroll
      for (int mt = 0; mt < 2; ++mt)
        liacc[mt] = __builtin_amdgcn_mfma_f32_16x16x32_f16(pf[mt], ones, liacc[mt], 0, 0, 0);
      #pragma unroll
      for (int ntg = 0; ntg < 2; ++ntg) {
        f16x8 vf[4];
        #pragma unroll
        for (int j = 0; j < 4; ++j) {
          int rv = (ntg * 4 + j) * 16 + l15;
          int pv = (k2 * 4 + quad) ^ (rv & 7);
          vf[j] = *(const f16x8*)((const char*)Vs + rv * 128 + pv * 16);
        }
        __builtin_amdgcn_s_setprio(1);
        #pragma unroll
        for (int mt = 0; mt < 2; ++mt)
          #pragma unroll
          for (int j = 0; j < 4; ++j)
            oacc[mt][ntg * 4 + j] = __builtin_amdgcn_mfma_f32_16x16x32_f16(pf[mt], vf[j], oacc[mt][ntg * 4 + j], 0, 0, 0);
        __builtin_amdgcn_s_setprio(0);
      }
    }

    // barrier B: all waves done reading V[kt]; drains K[kt+1] stage
    __syncthreads();
    if (kt + 1 < nkt) stageV(kt + 1);   // covered by next QK, drained at barrier A
  }

  // epilogue: O / l  (liacc columns identical; lane reads its own)
  #pragma unroll
  for (int mt = 0; mt < 2; ++mt)
    #pragma unroll
    for (int r = 0; r < 4; ++r) {
      float inv = 1.0f / liacc[mt][r];
      size_t row = (size_t)b * S + qt * 128 + wave * 32 + mt * 16 + quad * 4 + r;
      #pragma unroll
      for (int nt = 0; nt < 8; ++nt)
        O[row * 4096 + hq * 128 + nt * 16 + l15] = (_Float16)(oacc[mt][nt][r] * inv);
    }
}

extern "C" void kernel_launch(void* const* d_in, const int* in_sizes, int n_in,
                              void* d_out, int out_size, void* d_ws, size_t ws_size,
                              hipStream_t stream) {
  const float* x  = (const float*)d_in[0];
  const float* wq = (const float*)d_in[1];
  const float* wk = (const float*)d_in[2];
  const float* wv = (const float*)d_in[3];
  const float* wo = (const float*)d_in[4];
  const int*   sp = (const int*)d_in[5];

  const int dim = 4096, kvdim = 1024;
  const int T = in_sizes[0] / dim;   // 4096 tokens (b*s)
  const int B = 2;
  const int S = T / B;               // 2048

  // workspace layout (fp16), total ~160 MiB
  _Float16* xb   = (_Float16*)d_ws;
  _Float16* wqb  = xb   + (size_t)T * dim;
  _Float16* wkvb = wqb  + (size_t)dim * dim;
  _Float16* wob  = wkvb + (size_t)2 * kvdim * dim;
  _Float16* XQ   = wob  + (size_t)dim * dim;
  _Float16* XK   = XQ   + (size_t)T * dim;
  _Float16* VT   = XK   + (size_t)T * kvdim;
  _Float16* AO   = xb;               // alias: xb dead after projections

  auto cvt = [&](const float* src, _Float16* dst, size_t n) {
    int n4 = (int)(n / 4);
    int blocks = (n4 + 255) / 256;
    if (blocks > 4096) blocks = 4096;
    cvt_kernel<<<blocks, 256, 0, stream>>>(src, dst, n4);
  };
  cvt(x,  xb,  (size_t)T * dim);
  cvt(wq, wqb, (size_t)dim * dim);
  cvt(wk, wkvb, (size_t)kvdim * dim);
  cvt(wv, wkvb + (size_t)kvdim * dim, (size_t)kvdim * dim);
  cvt(wo, wob, (size_t)dim * dim);

  // projections
  gemm_nt<0><<<dim3(dim / 128, T / 128), 256, 0, stream>>>(xb, wqb, XQ, nullptr, T, dim, dim);
  gemm_nt<3><<<dim3((2 * kvdim) / 128, T / 128), 256, 0, stream>>>(xb, wkvb, XK, VT, T, 2 * kvdim, dim);

  // RoPE (in place)
  rope_kernel<<<4096, 256, 0, stream>>>(XQ, sp, 11, S - 1, T * dim / 2);
  rope_kernel<<<2048, 256, 0, stream>>>(XK, sp,  9, S - 1, T * kvdim / 2);

  // attention
  flash_kernel<<<dim3(S / 128, 32, B), 256, 0, stream>>>(XQ, XK, VT, AO, S, T);

  // output projection (fp32 out)
  gemm_nt<2><<<dim3(dim / 128, T / 128), 256, 0, stream>>>(AO, wob, d_out, nullptr, T, dim, dim);
}

// Round 5
// 845.167 us; speedup vs baseline: 1.9714x; 1.0220x over previous
//
#include <hip/hip_runtime.h>
#include <cstdint>
#include <cstddef>

typedef _Float16 f16x8 __attribute__((ext_vector_type(8)));
typedef _Float16 f16x4 __attribute__((ext_vector_type(4)));
typedef _Float16 f16x2 __attribute__((ext_vector_type(2)));
typedef float    f32x4 __attribute__((ext_vector_type(4)));
typedef uint32_t u32x4 __attribute__((ext_vector_type(4)));

__device__ __forceinline__ void async16(const void* g, void* l) {
  __builtin_amdgcn_global_load_lds(
      (const __attribute__((address_space(1))) void*)g,
      (__attribute__((address_space(3))) void*)l, 16, 0, 0);
}

// ---------------- fp32 -> fp16 convert ----------------
__global__ void cvt_kernel(const float* __restrict__ in, _Float16* __restrict__ out, int n4) {
  int i = blockIdx.x * blockDim.x + threadIdx.x;
  int stride = gridDim.x * blockDim.x;
  for (; i < n4; i += stride) {
    float4 f = ((const float4*)in)[i];
    f16x4 o;
    o[0] = (_Float16)f.x; o[1] = (_Float16)f.y;
    o[2] = (_Float16)f.z; o[3] = (_Float16)f.w;
    ((f16x4*)out)[i] = o;
  }
}

// ---------------- RoPE, interleaved pairs, in place ----------------
__global__ void rope_kernel(_Float16* __restrict__ X, const int* __restrict__ sp,
                            int ppShift, int sMask, int nPairs) {
  int i = blockIdx.x * blockDim.x + threadIdx.x;
  int stride = gridDim.x * blockDim.x;
  int start = *sp;
  for (int p = i; p < nPairs; p += stride) {
    int row = p >> ppShift;
    int pc  = p & ((1 << ppShift) - 1);
    int fi  = pc & 63;                 // pair index within head (d/2 = 64)
    int s   = row & sMask;             // row = b*S + s
    float ang = (float)(start + s) * exp2f(-0.20762050593046014f * (float)fi);
    float sn, cs;
    __sincosf(ang, &sn, &cs);
    uint32_t u = ((uint32_t*)X)[p];
    f16x2 v = __builtin_bit_cast(f16x2, u);
    float x1 = (float)v[0], x2 = (float)v[1];
    v[0] = (_Float16)(x1 * cs - x2 * sn);
    v[1] = (_Float16)(x1 * sn + x2 * cs);
    ((uint32_t*)X)[p] = __builtin_bit_cast(uint32_t, v);
  }
}

// ---------------- NT GEMM: C = A(M,K) * B(N,K)^T ----------------
// OUT_MODE 0: f16 C row-major (ld=N)
// OUT_MODE 2: f32 C row-major (ld=N)
// OUT_MODE 3: split KV: cols [0,N/2) -> f16 Cp (ld=N/2); cols [N/2,N) -> f16 Cp2 transposed (ld=M)
template<int OUT_MODE>
__global__ __launch_bounds__(256, 3)
void gemm_nt(const _Float16* __restrict__ A, const _Float16* __restrict__ B,
             void* __restrict__ Cp, void* __restrict__ Cp2,
             int M, int N, int K) {
  __shared__ __align__(16) _Float16 As[128 * 64];
  __shared__ __align__(16) _Float16 Bs[128 * 64];
  const int tid  = threadIdx.x;
  const int wave = tid >> 6, lane = tid & 63;
  const int l15  = lane & 15, quad = lane >> 4;
  const int m0 = blockIdx.y * 128, n0 = blockIdx.x * 128;
  const int wm = (wave >> 1) * 64, wn = (wave & 1) * 64;
  f32x4 acc[4][4] = {};
  const int cbase = wave * 256;

  for (int kb = 0; kb < K; kb += 64) {
    // stage A,B tiles (128x64 f16 each) via global_load_lds, XOR chunk swizzle
    #pragma unroll
    for (int i = 0; i < 4; ++i) {
      int base = cbase + i * 64;
      int idx  = base + lane;          // chunk 0..1023
      int row  = idx >> 3, pos = idx & 7;
      int c    = pos ^ (row & 7);
      async16(A + (size_t)(m0 + row) * K + kb + c * 8, (char*)As + base * 16);
      async16(B + (size_t)(n0 + row) * K + kb + c * 8, (char*)Bs + base * 16);
    }
    __syncthreads();
    #pragma unroll
    for (int ks = 0; ks < 2; ++ks) {
      f16x8 af[4], bfv[4];
      #pragma unroll
      for (int t = 0; t < 4; ++t) {
        int ra = wm + t * 16 + l15;
        int pa = (ks * 4 + quad) ^ (ra & 7);
        af[t] = *(const f16x8*)((const char*)As + ra * 128 + pa * 16);
        int rb = wn + t * 16 + l15;
        int pb = (ks * 4 + quad) ^ (rb & 7);
        bfv[t] = *(const f16x8*)((const char*)Bs + rb * 128 + pb * 16);
      }
      #pragma unroll
      for (int mt = 0; mt < 4; ++mt)
        #pragma unroll
        for (int nt = 0; nt < 4; ++nt)
          acc[mt][nt] = __builtin_amdgcn_mfma_f32_16x16x32_f16(af[mt], bfv[nt], acc[mt][nt], 0, 0, 0);
    }
    __syncthreads();
  }

  if constexpr (OUT_MODE == 0) {
    _Float16* Cb = (_Float16*)Cp;
    #pragma unroll
    for (int mt = 0; mt < 4; ++mt)
      #pragma unroll
      for (int r = 0; r < 4; ++r) {
        size_t row = (size_t)(m0 + wm + mt * 16 + quad * 4 + r);
        #pragma unroll
        for (int nt = 0; nt < 4; ++nt)
          Cb[row * N + n0 + wn + nt * 16 + l15] = (_Float16)acc[mt][nt][r];
      }
  } else if constexpr (OUT_MODE == 2) {
    float* Cf = (float*)Cp;
    #pragma unroll
    for (int mt = 0; mt < 4; ++mt)
      #pragma unroll
      for (int r = 0; r < 4; ++r) {
        size_t row = (size_t)(m0 + wm + mt * 16 + quad * 4 + r);
        #pragma unroll
        for (int nt = 0; nt < 4; ++nt)
          Cf[row * N + n0 + wn + nt * 16 + l15] = acc[mt][nt][r];
      }
  } else if constexpr (OUT_MODE == 3) {
    const int half = N >> 1;
    if (n0 < half) {           // K-projection half: normal f16 store, ld = half
      _Float16* Cb = (_Float16*)Cp;
      #pragma unroll
      for (int mt = 0; mt < 4; ++mt)
        #pragma unroll
        for (int r = 0; r < 4; ++r) {
          size_t row = (size_t)(m0 + wm + mt * 16 + quad * 4 + r);
          #pragma unroll
          for (int nt = 0; nt < 4; ++nt)
            Cb[row * half + n0 + wn + nt * 16 + l15] = (_Float16)acc[mt][nt][r];
        }
    } else {                   // V-projection half: store transposed (feature-major)
      _Float16* Ct = (_Float16*)Cp2;
      #pragma unroll
      for (int mt = 0; mt < 4; ++mt)
        #pragma unroll
        for (int nt = 0; nt < 4; ++nt) {
          size_t crow = (size_t)(n0 - half + wn + nt * 16 + l15);
          size_t ccol = (size_t)(m0 + wm + mt * 16 + quad * 4);
          f16x4 t;
          t[0] = (_Float16)acc[mt][nt][0]; t[1] = (_Float16)acc[mt][nt][1];
          t[2] = (_Float16)acc[mt][nt][2]; t[3] = (_Float16)acc[mt][nt][3];
          *(f16x4*)(Ct + crow * M + ccol) = t;
        }
    }
  }
}

// ---------------- flash attention, non-causal, GQA 4:1 ----------------
// Q: (T, 4096) roped; Kg: (T, 1024) roped; Vt: (1024, T) transposed; O: (T, 4096)
// SWAPPED QK^T: sacc = mfma(K, Q) puts q on l15 (C cols), keys on quad*4+r.
//  - softmax row-reduce: 16 lane-local values + 2 shfl_xor (vs 32-shfl butterfly)
//  - P already has the PV A-operand lane mapping (l15=q); quad-group
//    redistribution via 16 shfl+8 sel per mt rebuilds exact A-fragments
//    in-register -> Ps LDS buffer and its 32 ds_write/4 ds_read per iter die.
//    (mapping: pf[j]=P[q=l15][key=k2*32+quad*8+j]; src lane=((quad&1)*2+(j>>2))*16+l15,
//     nt_s=2*k2+(quad>>1), r_s=j&3 -> idxA/idxB + hiNt select)
// LDS 32KB (K+V only) -> 1024-block grid fits in ONE generation at 4 blocks/CU
// if VGPR<=128 (kills the 3+1 generation tail seen in R3's 21% occupancy).
// launch_bounds stays (256,2) -- R2 lesson: forcing 3 via launch_bounds spills.
__global__ __launch_bounds__(256, 2)
void flash_kernel(const _Float16* __restrict__ Q, const _Float16* __restrict__ Kg,
                  const _Float16* __restrict__ Vt, _Float16* __restrict__ O,
                  int S, int T) {
  __shared__ __align__(16) _Float16 Kt[64 * 128];   // [key][d], swizzled
  __shared__ __align__(16) _Float16 Vs[128 * 64];   // [d][key], swizzled
  const int tid  = threadIdx.x;
  const int wave = tid >> 6, lane = tid & 63;
  const int l15  = lane & 15, quad = lane >> 4;
  const int qt = blockIdx.x, hq = blockIdx.y, b = blockIdx.z;
  const int kvh = hq >> 2;
  const float scale = 0.12751744f;   // log2(e)/sqrt(128): softmax in exp2 domain

  // Q fragments in registers: wave owns 32 q-rows (q = mt*16 + l15)
  f16x8 qf[2][4];
  #pragma unroll
  for (int mt = 0; mt < 2; ++mt)
    #pragma unroll
    for (int ks = 0; ks < 4; ++ks) {
      size_t row = (size_t)b * S + qt * 128 + wave * 32 + mt * 16 + l15;
      qf[mt][ks] = *(const f16x8*)(Q + row * 4096 + hq * 128 + ks * 32 + quad * 8);
    }

  const f16x8 ones = {(_Float16)1, (_Float16)1, (_Float16)1, (_Float16)1,
                      (_Float16)1, (_Float16)1, (_Float16)1, (_Float16)1};

  f32x4 oacc[2][8] = {};
  f32x4 liacc[2] = {};              // row-sums via MFMA(P, ones): q = quad*4+r
  float mi[2] = {-1e30f, -1e30f};   // running max, lane-local (q = l15)

  const int nkt = S >> 6;

  auto stageK = [&](int kt) {
    #pragma unroll
    for (int i = 0; i < 4; ++i) {
      int base = wave * 256 + i * 64;
      int idx  = base + lane;
      int row = idx >> 4, pos = idx & 15, c = pos ^ (row & 15);
      async16(Kg + (size_t)(b * S + kt * 64 + row) * 1024 + kvh * 128 + c * 8,
              (char*)Kt + base * 16);
    }
  };
  auto stageV = [&](int kt) {
    #pragma unroll
    for (int i = 0; i < 4; ++i) {
      int base = wave * 256 + i * 64;
      int idx  = base + lane;
      int row = idx >> 3, pos = idx & 7, c = pos ^ (row & 7);
      async16(Vt + (size_t)(kvh * 128 + row) * T + b * S + kt * 64 + c * 8,
              (char*)Vs + base * 16);
    }
  };

  stageK(0); stageV(0);
  __syncthreads();           // drain prologue

  // P redistribution source lanes (quad-group permute within same l15)
  const int idxA = l15 + (((quad * 2) & 3) << 4);      // elems j0..3
  const int idxB = l15 + (((quad * 2 + 1) & 3) << 4);  // elems j4..7
  const bool hiNt = (quad >> 1) != 0;                  // nt_s = 2*k2 + (quad>>1)

  for (int kt = 0; kt < nkt; ++kt) {
    // ---- S^T = K Q^T: sacc[mt][nt] holds S[key=nt*16+quad*4+r][q=mt*16+l15] ----
    f32x4 sacc[2][4] = {};
    #pragma unroll
    for (int ks = 0; ks < 4; ++ks) {
      f16x8 kf[4];
      #pragma unroll
      for (int nt = 0; nt < 4; ++nt) {
        int rk = nt * 16 + l15;
        int pp = (ks * 4 + quad) ^ (rk & 15);
        kf[nt] = *(const f16x8*)((const char*)Kt + rk * 256 + pp * 16);
      }
      __builtin_amdgcn_s_setprio(1);
      #pragma unroll
      for (int mt = 0; mt < 2; ++mt)
        #pragma unroll
        for (int nt = 0; nt < 4; ++nt)
          sacc[mt][nt] = __builtin_amdgcn_mfma_f32_16x16x32_f16(kf[nt], qf[mt][ks], sacc[mt][nt], 0, 0, 0);
      __builtin_amdgcn_s_setprio(0);
    }

    // barrier A: all waves done reading K[kt]; drains V[kt] stage (issued last iter)
    __syncthreads();
    if (kt + 1 < nkt) stageK(kt + 1);   // covered by softmax+PV, drained at barrier B

    // ---- softmax + in-register P -> A-fragment rebuild ----
    f16x8 pf[2][2];
    #pragma unroll
    for (int mt = 0; mt < 2; ++mt) {
      // lane-local max over 16 keys (balanced tree), then 2-step quad butterfly
      float a0 = fmaxf(fmaxf(sacc[mt][0][0], sacc[mt][0][1]), fmaxf(sacc[mt][0][2], sacc[mt][0][3]));
      float a1 = fmaxf(fmaxf(sacc[mt][1][0], sacc[mt][1][1]), fmaxf(sacc[mt][1][2], sacc[mt][1][3]));
      float a2 = fmaxf(fmaxf(sacc[mt][2][0], sacc[mt][2][1]), fmaxf(sacc[mt][2][2], sacc[mt][2][3]));
      float a3 = fmaxf(fmaxf(sacc[mt][3][0], sacc[mt][3][1]), fmaxf(sacc[mt][3][2], sacc[mt][3][3]));
      float mx = fmaxf(fmaxf(a0, a1), fmaxf(a2, a3));
      mx = fmaxf(mx, __shfl_xor(mx, 16));
      mx = fmaxf(mx, __shfl_xor(mx, 32));
      // defer-max: rescale only when running max grew materially (24 raw ~ 2^3)
      if (__any(mx > mi[mt] + 24.0f)) {
        float mnew = fmaxf(mi[mt], mx);
        float al = exp2f((mi[mt] - mnew) * scale);
        mi[mt] = mnew;
        #pragma unroll
        for (int r = 0; r < 4; ++r) {
          float alr = __shfl(al, quad * 4 + r);   // al for q = quad*4+r
          liacc[mt][r] *= alr;
          #pragma unroll
          for (int nt = 0; nt < 8; ++nt) oacc[mt][nt][r] *= alr;
        }
      }
      float nm = -mi[mt] * scale;
      #pragma unroll
      for (int nt = 0; nt < 4; ++nt)
        #pragma unroll
        for (int r = 0; r < 4; ++r)
          sacc[mt][nt][r] = exp2f(fmaf(sacc[mt][nt][r], scale, nm));
      // pack to f16x2 dwords: pd[nt][h] = (p[2h], p[2h+1]) for keys nt*16+quad*4+{2h,2h+1}
      uint32_t pd[4][2];
      #pragma unroll
      for (int nt = 0; nt < 4; ++nt) {
        f16x2 lo2, hi2;
        lo2[0] = (_Float16)sacc[mt][nt][0]; lo2[1] = (_Float16)sacc[mt][nt][1];
        hi2[0] = (_Float16)sacc[mt][nt][2]; hi2[1] = (_Float16)sacc[mt][nt][3];
        pd[nt][0] = __builtin_bit_cast(uint32_t, lo2);
        pd[nt][1] = __builtin_bit_cast(uint32_t, hi2);
      }
      // rebuild A-fragments: pf[mt][k2][j] = P[q=l15][key = k2*32 + quad*8 + j]
      #pragma unroll
      for (int k2 = 0; k2 < 2; ++k2) {
        uint32_t w[4];
        #pragma unroll
        for (int h = 0; h < 2; ++h) {
          uint32_t a0v = (uint32_t)__shfl((int)pd[2 * k2][h],     idxA);
          uint32_t a1v = (uint32_t)__shfl((int)pd[2 * k2 + 1][h], idxA);
          w[h] = hiNt ? a1v : a0v;
          uint32_t b0v = (uint32_t)__shfl((int)pd[2 * k2][h],     idxB);
          uint32_t b1v = (uint32_t)__shfl((int)pd[2 * k2 + 1][h], idxB);
          w[2 + h] = hiNt ? b1v : b0v;
        }
        u32x4 wv = {w[0], w[1], w[2], w[3]};
        pf[mt][k2] = __builtin_bit_cast(f16x8, wv);
      }
    }

    // ---- O += P V ; li += P*1 ----
    #pragma unroll
    for (int k2 = 0; k2 < 2; ++k2) {
      f16x8 vf[8];
      #pragma unroll
      for (int nt = 0; nt < 8; ++nt) {
        int rv = nt * 16 + l15;
        int pv = (k2 * 4 + quad) ^ (rv & 7);
        vf[nt] = *(const f16x8*)((const char*)Vs + rv * 128 + pv * 16);
      }
      __builtin_amdgcn_s_setprio(1);
      #pragma unroll
      for (int mt = 0; mt < 2; ++mt)
        liacc[mt] = __builtin_amdgcn_mfma_f32_16x16x32_f16(pf[mt][k2], ones, liacc[mt], 0, 0, 0);
      #pragma unroll
      for (int mt = 0; mt < 2; ++mt)
        #pragma unroll
        for (int nt = 0; nt < 8; ++nt)
          oacc[mt][nt] = __builtin_amdgcn_mfma_f32_16x16x32_f16(pf[mt][k2], vf[nt], oacc[mt][nt], 0, 0, 0);
      __builtin_amdgcn_s_setprio(0);
    }

    // barrier B: all waves done reading V[kt]; drains K[kt+1] stage
    __syncthreads();
    if (kt + 1 < nkt) stageV(kt + 1);   // covered by next QK, drained at barrier A
  }

  // epilogue: O / l  (oacc/liacc row q = quad*4+r, col d = nt*16+l15)
  #pragma unroll
  for (int mt = 0; mt < 2; ++mt)
    #pragma unroll
    for (int r = 0; r < 4; ++r) {
      float inv = 1.0f / liacc[mt][r];
      size_t row = (size_t)b * S + qt * 128 + wave * 32 + mt * 16 + quad * 4 + r;
      #pragma unroll
      for (int nt = 0; nt < 8; ++nt)
        O[row * 4096 + hq * 128 + nt * 16 + l15] = (_Float16)(oacc[mt][nt][r] * inv);
    }
}

extern "C" void kernel_launch(void* const* d_in, const int* in_sizes, int n_in,
                              void* d_out, int out_size, void* d_ws, size_t ws_size,
                              hipStream_t stream) {
  const float* x  = (const float*)d_in[0];
  const float* wq = (const float*)d_in[1];
  const float* wk = (const float*)d_in[2];
  const float* wv = (const float*)d_in[3];
  const float* wo = (const float*)d_in[4];
  const int*   sp = (const int*)d_in[5];

  const int dim = 4096, kvdim = 1024;
  const int T = in_sizes[0] / dim;   // 4096 tokens (b*s)
  const int B = 2;
  const int S = T / B;               // 2048

  // workspace layout (fp16), total ~160 MiB
  _Float16* xb   = (_Float16*)d_ws;
  _Float16* wqb  = xb   + (size_t)T * dim;
  _Float16* wkvb = wqb  + (size_t)dim * dim;
  _Float16* wob  = wkvb + (size_t)2 * kvdim * dim;
  _Float16* XQ   = wob  + (size_t)dim * dim;
  _Float16* XK   = XQ   + (size_t)T * dim;
  _Float16* VT   = XK   + (size_t)T * kvdim;
  _Float16* AO   = xb;               // alias: xb dead after projections

  auto cvt = [&](const float* src, _Float16* dst, size_t n) {
    int n4 = (int)(n / 4);
    int blocks = (n4 + 255) / 256;
    if (blocks > 4096) blocks = 4096;
    cvt_kernel<<<blocks, 256, 0, stream>>>(src, dst, n4);
  };
  cvt(x,  xb,  (size_t)T * dim);
  cvt(wq, wqb, (size_t)dim * dim);
  cvt(wk, wkvb, (size_t)kvdim * dim);
  cvt(wv, wkvb + (size_t)kvdim * dim, (size_t)kvdim * dim);
  cvt(wo, wob, (size_t)dim * dim);

  // projections
  gemm_nt<0><<<dim3(dim / 128, T / 128), 256, 0, stream>>>(xb, wqb, XQ, nullptr, T, dim, dim);
  gemm_nt<3><<<dim3((2 * kvdim) / 128, T / 128), 256, 0, stream>>>(xb, wkvb, XK, VT, T, 2 * kvdim, dim);

  // RoPE (in place)
  rope_kernel<<<4096, 256, 0, stream>>>(XQ, sp, 11, S - 1, T * dim / 2);
  rope_kernel<<<2048, 256, 0, stream>>>(XK, sp,  9, S - 1, T * kvdim / 2);

  // attention
  flash_kernel<<<dim3(S / 128, 32, B), 256, 0, stream>>>(XQ, XK, VT, AO, S, T);

  // output projection (fp32 out)
  gemm_nt<2><<<dim3(dim / 128, T / 128), 256, 0, stream>>>(AO, wob, d_out, nullptr, T, dim, dim);
}

// Round 6
// 762.857 us; speedup vs baseline: 2.1841x; 1.1079x over previous
//
#include <hip/hip_runtime.h>
#include <cstdint>
#include <cstddef>

typedef _Float16 f16x8 __attribute__((ext_vector_type(8)));
typedef _Float16 f16x4 __attribute__((ext_vector_type(4)));
typedef _Float16 f16x2 __attribute__((ext_vector_type(2)));
typedef float    f32x4 __attribute__((ext_vector_type(4)));
typedef uint32_t u32x4 __attribute__((ext_vector_type(4)));

__device__ __forceinline__ void async16(const void* g, void* l) {
  __builtin_amdgcn_global_load_lds(
      (const __attribute__((address_space(1))) void*)g,
      (__attribute__((address_space(3))) void*)l, 16, 0, 0);
}

// ---------------- fused fp32 -> fp16 convert, 5 segments in one launch ----------------
__global__ void cvt5_kernel(const float* __restrict__ s0, const float* __restrict__ s1,
                            const float* __restrict__ s2, const float* __restrict__ s3,
                            const float* __restrict__ s4,
                            _Float16* __restrict__ d0, _Float16* __restrict__ d1,
                            _Float16* __restrict__ d2, _Float16* __restrict__ d3,
                            _Float16* __restrict__ d4,
                            int n0, int n1, int n2, int n3, int n4c) {
  const float* src; _Float16* dst; int n4;
  switch (blockIdx.y) {
    case 0:  src = s0; dst = d0; n4 = n0;  break;
    case 1:  src = s1; dst = d1; n4 = n1;  break;
    case 2:  src = s2; dst = d2; n4 = n2;  break;
    case 3:  src = s3; dst = d3; n4 = n3;  break;
    default: src = s4; dst = d4; n4 = n4c; break;
  }
  int i = blockIdx.x * blockDim.x + threadIdx.x;
  int stride = gridDim.x * blockDim.x;
  for (; i < n4; i += stride) {
    float4 f = ((const float4*)src)[i];
    f16x4 o;
    o[0] = (_Float16)f.x; o[1] = (_Float16)f.y;
    o[2] = (_Float16)f.z; o[3] = (_Float16)f.w;
    ((f16x4*)dst)[i] = o;
  }
}

// ---------------- RoPE, interleaved pairs, in place, XQ+XK in one launch ----------------
__global__ void rope2_kernel(_Float16* __restrict__ XQ, _Float16* __restrict__ XK,
                             const int* __restrict__ sp, int sMask,
                             int nPairsQ, int nPairsK) {
  _Float16* X; int ppShift, nPairs;
  if (blockIdx.y == 0) { X = XQ; ppShift = 11; nPairs = nPairsQ; }
  else                 { X = XK; ppShift = 9;  nPairs = nPairsK; }
  int i = blockIdx.x * blockDim.x + threadIdx.x;
  int stride = gridDim.x * blockDim.x;
  int start = *sp;
  for (int p = i; p < nPairs; p += stride) {
    int row = p >> ppShift;
    int pc  = p & ((1 << ppShift) - 1);
    int fi  = pc & 63;                 // pair index within head (d/2 = 64)
    int s   = row & sMask;             // row = b*S + s
    float ang = (float)(start + s) * exp2f(-0.20762050593046014f * (float)fi);
    float sn, cs;
    __sincosf(ang, &sn, &cs);
    uint32_t u = ((uint32_t*)X)[p];
    f16x2 v = __builtin_bit_cast(f16x2, u);
    float x1 = (float)v[0], x2 = (float)v[1];
    v[0] = (_Float16)(x1 * cs - x2 * sn);
    v[1] = (_Float16)(x1 * sn + x2 * cs);
    ((uint32_t*)X)[p] = __builtin_bit_cast(uint32_t, v);
  }
}

// ---------------- NT GEMM: C = A(M,K) * B(N,K)^T ----------------
// OUT_MODE 2: f32 C row-major (ld=N)
// OUT_MODE 4: fused QKV epilogue: cols [0,4096) -> f16 Cp (XQ, ld=4096);
//             [4096,5120) -> f16 Cp2 (XK, ld=1024); [5120,6144) -> f16 Cp3
//             transposed (VT, ld=M)
template<int OUT_MODE>
__global__ __launch_bounds__(256, 3)
void gemm_nt(const _Float16* __restrict__ A, const _Float16* __restrict__ B,
             void* __restrict__ Cp, void* __restrict__ Cp2, void* __restrict__ Cp3,
             int M, int N, int K) {
  __shared__ __align__(16) _Float16 As[128 * 64];
  __shared__ __align__(16) _Float16 Bs[128 * 64];
  const int tid  = threadIdx.x;
  const int wave = tid >> 6, lane = tid & 63;
  const int l15  = lane & 15, quad = lane >> 4;
  const int m0 = blockIdx.y * 128, n0 = blockIdx.x * 128;
  const int wm = (wave >> 1) * 64, wn = (wave & 1) * 64;
  f32x4 acc[4][4] = {};
  const int cbase = wave * 256;

  for (int kb = 0; kb < K; kb += 64) {
    // stage A,B tiles (128x64 f16 each) via global_load_lds, XOR chunk swizzle
    #pragma unroll
    for (int i = 0; i < 4; ++i) {
      int base = cbase + i * 64;
      int idx  = base + lane;          // chunk 0..1023
      int row  = idx >> 3, pos = idx & 7;
      int c    = pos ^ (row & 7);
      async16(A + (size_t)(m0 + row) * K + kb + c * 8, (char*)As + base * 16);
      async16(B + (size_t)(n0 + row) * K + kb + c * 8, (char*)Bs + base * 16);
    }
    __syncthreads();
    #pragma unroll
    for (int ks = 0; ks < 2; ++ks) {
      f16x8 af[4], bfv[4];
      #pragma unroll
      for (int t = 0; t < 4; ++t) {
        int ra = wm + t * 16 + l15;
        int pa = (ks * 4 + quad) ^ (ra & 7);
        af[t] = *(const f16x8*)((const char*)As + ra * 128 + pa * 16);
        int rb = wn + t * 16 + l15;
        int pb = (ks * 4 + quad) ^ (rb & 7);
        bfv[t] = *(const f16x8*)((const char*)Bs + rb * 128 + pb * 16);
      }
      #pragma unroll
      for (int mt = 0; mt < 4; ++mt)
        #pragma unroll
        for (int nt = 0; nt < 4; ++nt)
          acc[mt][nt] = __builtin_amdgcn_mfma_f32_16x16x32_f16(af[mt], bfv[nt], acc[mt][nt], 0, 0, 0);
    }
    __syncthreads();
  }

  if constexpr (OUT_MODE == 2) {
    float* Cf = (float*)Cp;
    #pragma unroll
    for (int mt = 0; mt < 4; ++mt)
      #pragma unroll
      for (int r = 0; r < 4; ++r) {
        size_t row = (size_t)(m0 + wm + mt * 16 + quad * 4 + r);
        #pragma unroll
        for (int nt = 0; nt < 4; ++nt)
          Cf[row * N + n0 + wn + nt * 16 + l15] = acc[mt][nt][r];
      }
  } else if constexpr (OUT_MODE == 4) {
    if (n0 < 4096) {           // Q projection: f16, ld = 4096
      _Float16* Cb = (_Float16*)Cp;
      #pragma unroll
      for (int mt = 0; mt < 4; ++mt)
        #pragma unroll
        for (int r = 0; r < 4; ++r) {
          size_t row = (size_t)(m0 + wm + mt * 16 + quad * 4 + r);
          #pragma unroll
          for (int nt = 0; nt < 4; ++nt)
            Cb[row * 4096 + n0 + wn + nt * 16 + l15] = (_Float16)acc[mt][nt][r];
        }
    } else if (n0 < 5120) {    // K projection: f16, ld = 1024
      _Float16* Cb = (_Float16*)Cp2;
      #pragma unroll
      for (int mt = 0; mt < 4; ++mt)
        #pragma unroll
        for (int r = 0; r < 4; ++r) {
          size_t row = (size_t)(m0 + wm + mt * 16 + quad * 4 + r);
          #pragma unroll
          for (int nt = 0; nt < 4; ++nt)
            Cb[row * 1024 + (n0 - 4096) + wn + nt * 16 + l15] = (_Float16)acc[mt][nt][r];
        }
    } else {                   // V projection: store transposed (feature-major)
      _Float16* Ct = (_Float16*)Cp3;
      #pragma unroll
      for (int mt = 0; mt < 4; ++mt)
        #pragma unroll
        for (int nt = 0; nt < 4; ++nt) {
          size_t crow = (size_t)(n0 - 5120 + wn + nt * 16 + l15);
          size_t ccol = (size_t)(m0 + wm + mt * 16 + quad * 4);
          f16x4 t;
          t[0] = (_Float16)acc[mt][nt][0]; t[1] = (_Float16)acc[mt][nt][1];
          t[2] = (_Float16)acc[mt][nt][2]; t[3] = (_Float16)acc[mt][nt][3];
          *(f16x4*)(Ct + crow * M + ccol) = t;
        }
    }
  }
}

// ---------------- flash attention, non-causal, GQA 4:1 ----------------
// (unchanged from R5: verified swapped-QK^T, in-register P rebuild, 32KB LDS,
//  233us / MfmaUtil 27.8. Known cost: ~8.4M bank-conflict cycles from the
//  ds_bpermute P-redistribution ~= 14us total; accepted.)
__global__ __launch_bounds__(256, 2)
void flash_kernel(const _Float16* __restrict__ Q, const _Float16* __restrict__ Kg,
                  const _Float16* __restrict__ Vt, _Float16* __restrict__ O,
                  int S, int T) {
  __shared__ __align__(16) _Float16 Kt[64 * 128];   // [key][d], swizzled
  __shared__ __align__(16) _Float16 Vs[128 * 64];   // [d][key], swizzled
  const int tid  = threadIdx.x;
  const int wave = tid >> 6, lane = tid & 63;
  const int l15  = lane & 15, quad = lane >> 4;
  const int qt = blockIdx.x, hq = blockIdx.y, b = blockIdx.z;
  const int kvh = hq >> 2;
  const float scale = 0.12751744f;   // log2(e)/sqrt(128): softmax in exp2 domain

  // Q fragments in registers: wave owns 32 q-rows (q = mt*16 + l15)
  f16x8 qf[2][4];
  #pragma unroll
  for (int mt = 0; mt < 2; ++mt)
    #pragma unroll
    for (int ks = 0; ks < 4; ++ks) {
      size_t row = (size_t)b * S + qt * 128 + wave * 32 + mt * 16 + l15;
      qf[mt][ks] = *(const f16x8*)(Q + row * 4096 + hq * 128 + ks * 32 + quad * 8);
    }

  const f16x8 ones = {(_Float16)1, (_Float16)1, (_Float16)1, (_Float16)1,
                      (_Float16)1, (_Float16)1, (_Float16)1, (_Float16)1};

  f32x4 oacc[2][8] = {};
  f32x4 liacc[2] = {};              // row-sums via MFMA(P, ones): q = quad*4+r
  float mi[2] = {-1e30f, -1e30f};   // running max, lane-local (q = l15)

  const int nkt = S >> 6;

  auto stageK = [&](int kt) {
    #pragma unroll
    for (int i = 0; i < 4; ++i) {
      int base = wave * 256 + i * 64;
      int idx  = base + lane;
      int row = idx >> 4, pos = idx & 15, c = pos ^ (row & 15);
      async16(Kg + (size_t)(b * S + kt * 64 + row) * 1024 + kvh * 128 + c * 8,
              (char*)Kt + base * 16);
    }
  };
  auto stageV = [&](int kt) {
    #pragma unroll
    for (int i = 0; i < 4; ++i) {
      int base = wave * 256 + i * 64;
      int idx  = base + lane;
      int row = idx >> 3, pos = idx & 7, c = pos ^ (row & 7);
      async16(Vt + (size_t)(kvh * 128 + row) * T + b * S + kt * 64 + c * 8,
              (char*)Vs + base * 16);
    }
  };

  stageK(0); stageV(0);
  __syncthreads();           // drain prologue

  // P redistribution source lanes (quad-group permute within same l15)
  const int idxA = l15 + (((quad * 2) & 3) << 4);      // elems j0..3
  const int idxB = l15 + (((quad * 2 + 1) & 3) << 4);  // elems j4..7
  const bool hiNt = (quad >> 1) != 0;                  // nt_s = 2*k2 + (quad>>1)

  for (int kt = 0; kt < nkt; ++kt) {
    // ---- S^T = K Q^T: sacc[mt][nt] holds S[key=nt*16+quad*4+r][q=mt*16+l15] ----
    f32x4 sacc[2][4] = {};
    #pragma unroll
    for (int ks = 0; ks < 4; ++ks) {
      f16x8 kf[4];
      #pragma unroll
      for (int nt = 0; nt < 4; ++nt) {
        int rk = nt * 16 + l15;
        int pp = (ks * 4 + quad) ^ (rk & 15);
        kf[nt] = *(const f16x8*)((const char*)Kt + rk * 256 + pp * 16);
      }
      __builtin_amdgcn_s_setprio(1);
      #pragma unroll
      for (int mt = 0; mt < 2; ++mt)
        #pragma unroll
        for (int nt = 0; nt < 4; ++nt)
          sacc[mt][nt] = __builtin_amdgcn_mfma_f32_16x16x32_f16(kf[nt], qf[mt][ks], sacc[mt][nt], 0, 0, 0);
      __builtin_amdgcn_s_setprio(0);
    }

    // barrier A: all waves done reading K[kt]; drains V[kt] stage (issued last iter)
    __syncthreads();
    if (kt + 1 < nkt) stageK(kt + 1);   // covered by softmax+PV, drained at barrier B

    // ---- softmax + in-register P -> A-fragment rebuild ----
    f16x8 pf[2][2];
    #pragma unroll
    for (int mt = 0; mt < 2; ++mt) {
      // lane-local max over 16 keys (balanced tree), then 2-step quad butterfly
      float a0 = fmaxf(fmaxf(sacc[mt][0][0], sacc[mt][0][1]), fmaxf(sacc[mt][0][2], sacc[mt][0][3]));
      float a1 = fmaxf(fmaxf(sacc[mt][1][0], sacc[mt][1][1]), fmaxf(sacc[mt][1][2], sacc[mt][1][3]));
      float a2 = fmaxf(fmaxf(sacc[mt][2][0], sacc[mt][2][1]), fmaxf(sacc[mt][2][2], sacc[mt][2][3]));
      float a3 = fmaxf(fmaxf(sacc[mt][3][0], sacc[mt][3][1]), fmaxf(sacc[mt][3][2], sacc[mt][3][3]));
      float mx = fmaxf(fmaxf(a0, a1), fmaxf(a2, a3));
      mx = fmaxf(mx, __shfl_xor(mx, 16));
      mx = fmaxf(mx, __shfl_xor(mx, 32));
      // defer-max: rescale only when running max grew materially (24 raw ~ 2^3)
      if (__any(mx > mi[mt] + 24.0f)) {
        float mnew = fmaxf(mi[mt], mx);
        float al = exp2f((mi[mt] - mnew) * scale);
        mi[mt] = mnew;
        #pragma unroll
        for (int r = 0; r < 4; ++r) {
          float alr = __shfl(al, quad * 4 + r);   // al for q = quad*4+r
          liacc[mt][r] *= alr;
          #pragma unroll
          for (int nt = 0; nt < 8; ++nt) oacc[mt][nt][r] *= alr;
        }
      }
      float nm = -mi[mt] * scale;
      #pragma unroll
      for (int nt = 0; nt < 4; ++nt)
        #pragma unroll
        for (int r = 0; r < 4; ++r)
          sacc[mt][nt][r] = exp2f(fmaf(sacc[mt][nt][r], scale, nm));
      // pack to f16x2 dwords: pd[nt][h] = (p[2h], p[2h+1]) for keys nt*16+quad*4+{2h,2h+1}
      uint32_t pd[4][2];
      #pragma unroll
      for (int nt = 0; nt < 4; ++nt) {
        f16x2 lo2, hi2;
        lo2[0] = (_Float16)sacc[mt][nt][0]; lo2[1] = (_Float16)sacc[mt][nt][1];
        hi2[0] = (_Float16)sacc[mt][nt][2]; hi2[1] = (_Float16)sacc[mt][nt][3];
        pd[nt][0] = __builtin_bit_cast(uint32_t, lo2);
        pd[nt][1] = __builtin_bit_cast(uint32_t, hi2);
      }
      // rebuild A-fragments: pf[mt][k2][j] = P[q=l15][key = k2*32 + quad*8 + j]
      #pragma unroll
      for (int k2 = 0; k2 < 2; ++k2) {
        uint32_t w[4];
        #pragma unroll
        for (int h = 0; h < 2; ++h) {
          uint32_t a0v = (uint32_t)__shfl((int)pd[2 * k2][h],     idxA);
          uint32_t a1v = (uint32_t)__shfl((int)pd[2 * k2 + 1][h], idxA);
          w[h] = hiNt ? a1v : a0v;
          uint32_t b0v = (uint32_t)__shfl((int)pd[2 * k2][h],     idxB);
          uint32_t b1v = (uint32_t)__shfl((int)pd[2 * k2 + 1][h], idxB);
          w[2 + h] = hiNt ? b1v : b0v;
        }
        u32x4 wv = {w[0], w[1], w[2], w[3]};
        pf[mt][k2] = __builtin_bit_cast(f16x8, wv);
      }
    }

    // ---- O += P V ; li += P*1 ----
    #pragma unroll
    for (int k2 = 0; k2 < 2; ++k2) {
      f16x8 vf[8];
      #pragma unroll
      for (int nt = 0; nt < 8; ++nt) {
        int rv = nt * 16 + l15;
        int pv = (k2 * 4 + quad) ^ (rv & 7);
        vf[nt] = *(const f16x8*)((const char*)Vs + rv * 128 + pv * 16);
      }
      __builtin_amdgcn_s_setprio(1);
      #pragma unroll
      for (int mt = 0; mt < 2; ++mt)
        liacc[mt] = __builtin_amdgcn_mfma_f32_16x16x32_f16(pf[mt][k2], ones, liacc[mt], 0, 0, 0);
      #pragma unroll
      for (int mt = 0; mt < 2; ++mt)
        #pragma unroll
        for (int nt = 0; nt < 8; ++nt)
          oacc[mt][nt] = __builtin_amdgcn_mfma_f32_16x16x32_f16(pf[mt][k2], vf[nt], oacc[mt][nt], 0, 0, 0);
      __builtin_amdgcn_s_setprio(0);
    }

    // barrier B: all waves done reading V[kt]; drains K[kt+1] stage
    __syncthreads();
    if (kt + 1 < nkt) stageV(kt + 1);   // covered by next QK, drained at barrier A
  }

  // epilogue: O / l  (oacc/liacc row q = quad*4+r, col d = nt*16+l15)
  #pragma unroll
  for (int mt = 0; mt < 2; ++mt)
    #pragma unroll
    for (int r = 0; r < 4; ++r) {
      float inv = 1.0f / liacc[mt][r];
      size_t row = (size_t)b * S + qt * 128 + wave * 32 + mt * 16 + quad * 4 + r;
      #pragma unroll
      for (int nt = 0; nt < 8; ++nt)
        O[row * 4096 + hq * 128 + nt * 16 + l15] = (_Float16)(oacc[mt][nt][r] * inv);
    }
}

extern "C" void kernel_launch(void* const* d_in, const int* in_sizes, int n_in,
                              void* d_out, int out_size, void* d_ws, size_t ws_size,
                              hipStream_t stream) {
  const float* x  = (const float*)d_in[0];
  const float* wq = (const float*)d_in[1];
  const float* wk = (const float*)d_in[2];
  const float* wv = (const float*)d_in[3];
  const float* wo = (const float*)d_in[4];
  const int*   sp = (const int*)d_in[5];

  const int dim = 4096, kvdim = 1024;
  const int T = in_sizes[0] / dim;   // 4096 tokens (b*s)
  const int B = 2;
  const int S = T / B;               // 2048

  // workspace layout (fp16), total ~160 MiB
  _Float16* xb   = (_Float16*)d_ws;
  _Float16* wqb  = xb   + (size_t)T * dim;        // wq (4096 rows)
  _Float16* wkvb = wqb  + (size_t)dim * dim;      // wk (1024) then wv (1024), contiguous after wq
  _Float16* wob  = wkvb + (size_t)2 * kvdim * dim;
  _Float16* XQ   = wob  + (size_t)dim * dim;
  _Float16* XK   = XQ   + (size_t)T * dim;
  _Float16* VT   = XK   + (size_t)T * kvdim;
  _Float16* AO   = xb;               // alias: xb dead after projections

  // one launch: all five fp32->fp16 conversions
  cvt5_kernel<<<dim3(2048, 5), 256, 0, stream>>>(
      x, wq, wk, wv, wo,
      xb, wqb, wkvb, wkvb + (size_t)kvdim * dim, wob,
      (int)((size_t)T * dim / 4), (int)((size_t)dim * dim / 4),
      (int)((size_t)kvdim * dim / 4), (int)((size_t)kvdim * dim / 4),
      (int)((size_t)dim * dim / 4));

  // one launch: Q+K+V projections (wq|wk|wv contiguous as B rows [0,6144))
  gemm_nt<4><<<dim3((dim + 2 * kvdim) / 128, T / 128), 256, 0, stream>>>(
      xb, wqb, XQ, XK, VT, T, dim + 2 * kvdim, dim);

  // one launch: RoPE on XQ and XK (in place)
  rope2_kernel<<<dim3(4096, 2), 256, 0, stream>>>(
      XQ, XK, sp, S - 1, (int)((size_t)T * dim / 2), (int)((size_t)T * kvdim / 2));

  // attention
  flash_kernel<<<dim3(S / 128, 32, B), 256, 0, stream>>>(XQ, XK, VT, AO, S, T);

  // output projection (fp32 out)
  gemm_nt<2><<<dim3(dim / 128, T / 128), 256, 0, stream>>>(AO, wob, d_out, nullptr, nullptr, T, dim, dim);
}